// Round 1
// 531.349 us; speedup vs baseline: 1.1750x; 1.1750x over previous
//
#include <hip/hip_runtime.h>

typedef unsigned short u16;
typedef unsigned int u32;

#define N_NODES 20000
#define NE 320000
#define NLAYERS 4
#define NCLASS 40
#define NEG_SLOPE 0.2f
#define LSTRIDE ((NLAYERS + 1) * 128)  // 640 floats per node in X_all/Y_all

typedef __bf16 bf16x8 __attribute__((ext_vector_type(8)));
typedef float f32x4 __attribute__((ext_vector_type(4)));

__device__ inline u16 f2bf(float f) {
    u32 u = __float_as_uint(f);
    return (u16)((u + 0x7fffu + ((u >> 16) & 1u)) >> 16);  // round-nearest-even
}
__device__ inline float bf2f(u16 u) { return __uint_as_float(((u32)u) << 16); }

// ---------------- init: Xbf=bf16(x), X_all[:,0,:]=x, Y_all[:,0,:]=x ----------------
__global__ void k_init(const float* __restrict__ x, u16* __restrict__ Xbf,
                       float* __restrict__ Xall, float* __restrict__ Yall) {
    int t = blockIdx.x * 256 + threadIdx.x;
    if (t >= N_NODES * 128) return;
    float v = x[t];
    Xbf[t] = f2bf(v);
    int n = t >> 7, c = t & 127;
    int ob = n * LSTRIDE + c;  // layer-0 slot
    Xall[ob] = v;
    Yall[ob] = v;
}

// ---------------- Wt[512][128] = bf16(W^T) ----------------
__global__ void k_trans(const float* __restrict__ W, u16* __restrict__ Wt) {
    int t = blockIdx.x * 256 + threadIdx.x;  // 65536 threads
    int k = t >> 9, col = t & 511;
    Wt[col * 128 + k] = f2bf(W[t]);
}

// ---------------- fold attention vectors through W: Vs/Vd[128][4] (f32, exact path) ----
// one wave per (input-row t, head hd): 512 waves, shuffle-reduced 128-dot
__global__ __launch_bounds__(256) void k_fold(const float* __restrict__ W,
                                              const float* __restrict__ att_s,
                                              const float* __restrict__ att_d,
                                              float* __restrict__ Vs, float* __restrict__ Vd) {
    int wid = (blockIdx.x * 256 + threadIdx.x) >> 6;  // 0..511 = t*4+hd
    int lane = threadIdx.x & 63;
    int t = wid >> 2, hd = wid & 3;
    float w0 = W[t * 512 + hd * 128 + lane];
    float w1 = W[t * 512 + hd * 128 + 64 + lane];
    float s1 = w0 * att_s[hd * 128 + lane] + w1 * att_s[hd * 128 + 64 + lane];
    float s2 = w0 * att_d[hd * 128 + lane] + w1 * att_d[hd * 128 + 64 + lane];
    for (int off = 32; off; off >>= 1) {
        s1 += __shfl_xor(s1, off);
        s2 += __shfl_xor(s2, off);
    }
    if (lane == 0) {
        Vs[t * 4 + hd] = s1;
        Vd[t * 4 + hd] = s2;
    }
}

// ---------------- CSR build over dst (self loops included) ----------------
__global__ void k_ones(int* __restrict__ counts) {
    int t = blockIdx.x * 256 + threadIdx.x;
    if (t < N_NODES) counts[t] = 1;  // self loop
}
__global__ void k_count(const int* __restrict__ dst, int* __restrict__ counts) {
    int t = blockIdx.x * 256 + threadIdx.x;
    if (t < NE) atomicAdd(&counts[dst[t]], 1);
}
__global__ void k_scan(const int* __restrict__ counts, int* __restrict__ indptr,
                       int* __restrict__ cursor) {
    __shared__ int part[1024];
    int t = threadIdx.x;
    const int CH = 20;  // 1024*20 >= 20000
    int c0 = t * CH;
    int s = 0;
    for (int i = 0; i < CH; i++) {
        int idx = c0 + i;
        if (idx < N_NODES) s += counts[idx];
    }
    part[t] = s;
    __syncthreads();
    for (int off = 1; off < 1024; off <<= 1) {
        int v = 0;
        if (t >= off) v = part[t - off];
        __syncthreads();
        if (t >= off) part[t] += v;
        __syncthreads();
    }
    int ex = (t == 0) ? 0 : part[t - 1];
    for (int i = 0; i < CH; i++) {
        int idx = c0 + i;
        if (idx < N_NODES) {
            indptr[idx] = ex;
            cursor[idx] = ex;
            ex += counts[idx];
        }
    }
    if (t == 1023) indptr[N_NODES] = part[1023];
}
__global__ void k_scatter(const int* __restrict__ src, const int* __restrict__ dst,
                          int* __restrict__ cursor, int* __restrict__ esrc) {
    int t = blockIdx.x * 256 + threadIdx.x;
    if (t >= NE + N_NODES) return;
    int s, d;
    if (t < NE) { s = src[t]; d = dst[t]; }
    else { s = d = t - NE; }
    int pos = atomicAdd(&cursor[d], 1);
    esrc[pos] = s;
}

// ---------------- GEMM: hbf[N][512] = bf16(Xbf[N][128] @ W[128][512]), MFMA ----------------
__global__ __launch_bounds__(256) void k_gemm(const u16* __restrict__ Xbf,
                                              const u16* __restrict__ Wt,
                                              u16* __restrict__ hbf) {
    const int r0 = blockIdx.x * 64;
    const int c0 = blockIdx.y * 64;
    __shared__ u16 As[64 * 136];  // +8 pad breaks 256B-stride bank aliasing
    __shared__ u16 Bs[64 * 136];
    const int t = threadIdx.x;
    for (int i = 0; i < 4; i++) {
        int flat = i * 256 + t;  // 1024 chunks of 8 u16
        int row = flat >> 4;
        int kc = flat & 15;
        uint4 av = make_uint4(0u, 0u, 0u, 0u);
        int gr = r0 + row;
        if (gr < N_NODES) av = *(const uint4*)(Xbf + gr * 128 + kc * 8);
        *(uint4*)(As + row * 136 + kc * 8) = av;
        uint4 bv = *(const uint4*)(Wt + (c0 + row) * 128 + kc * 8);
        *(uint4*)(Bs + row * 136 + kc * 8) = bv;
    }
    __syncthreads();
    const int wave = t >> 6, lane = t & 63;
    const int wr = (wave >> 1) * 32, wc = (wave & 1) * 32;
    const int lrow = lane & 15, quad = lane >> 4;
    f32x4 acc[2][2] = {};
    for (int kk = 0; kk < 128; kk += 32) {
        bf16x8 a[2], b[2];
        for (int mi = 0; mi < 2; mi++)
            a[mi] = *(const bf16x8*)(As + (wr + mi * 16 + lrow) * 136 + kk + quad * 8);
        for (int ni = 0; ni < 2; ni++)
            b[ni] = *(const bf16x8*)(Bs + (wc + ni * 16 + lrow) * 136 + kk + quad * 8);
        for (int mi = 0; mi < 2; mi++)
            for (int ni = 0; ni < 2; ni++)
                acc[mi][ni] = __builtin_amdgcn_mfma_f32_16x16x32_bf16(a[mi], b[ni], acc[mi][ni], 0, 0, 0);
    }
    for (int mi = 0; mi < 2; mi++)
        for (int ni = 0; ni < 2; ni++)
            for (int r = 0; r < 4; r++) {
                int row = r0 + wr + mi * 16 + quad * 4 + r;
                int col = c0 + wc + ni * 16 + lrow;
                if (row < N_NODES) hbf[row * 512 + col] = f2bf(acc[mi][ni][r]);
            }
}

// ---------------- attention logits for layer 0: a_s/a_d[N][4] = X @ Vs/Vd ----------------
__global__ __launch_bounds__(256) void k_att(const float* __restrict__ Xall, int layer,
                                             const float* __restrict__ Vs,
                                             const float* __restrict__ Vd,
                                             float* __restrict__ a_s, float* __restrict__ a_d) {
    int wid = (blockIdx.x * 256 + threadIdx.x) >> 6;  // node, grid exact
    int lane = threadIdx.x & 63;
    const float* Xr = Xall + wid * LSTRIDE + layer * 128;
    float x0 = Xr[lane], x1 = Xr[64 + lane];
    f32x4 vs0 = *(const f32x4*)(Vs + lane * 4), vs1 = *(const f32x4*)(Vs + (64 + lane) * 4);
    f32x4 vd0 = *(const f32x4*)(Vd + lane * 4), vd1 = *(const f32x4*)(Vd + (64 + lane) * 4);
    f32x4 ps = x0 * vs0 + x1 * vs1;
    f32x4 pd = x0 * vd0 + x1 * vd1;
    for (int off = 32; off; off >>= 1)
        for (int c = 0; c < 4; c++) {
            ps[c] += __shfl_xor(ps[c], off);
            pd[c] += __shfl_xor(pd[c], off);
        }
    if (lane == 0) {
        *(f32x4*)(a_s + wid * 4) = ps;
        *(f32x4*)(a_d + wid * 4) = pd;
    }
}

// ---------------- fused per-dst-node: softmax + aggregate + epilogue + next-layer logits ----
__global__ __launch_bounds__(256) void k_aggr(
    const int* __restrict__ indptr, const int* __restrict__ esrc,
    const float* __restrict__ a_s, const float* __restrict__ a_d,
    const u16* __restrict__ hbf, const float* __restrict__ bias,
    u16* __restrict__ Xbf, float* __restrict__ Xall, float* __restrict__ Yall,
    float* __restrict__ a_s_nxt, float* __restrict__ a_d_nxt,
    const float* __restrict__ Vs, const float* __restrict__ Vd, int layer) {
    __shared__ int s_sh[4][66];
    __shared__ alignas(16) float al_sh[4][66][4];
    int d = (blockIdx.x * 256 + threadIdx.x) >> 6;  // grid exact: 5000 blocks -> 20000 waves
    int lane = threadIdx.x & 63;
    int w = threadIdx.x >> 6;
    int start = indptr[d], end = indptr[d + 1];
    int deg = end - start;
    f32x4 ad = *(const f32x4*)(a_d + d * 4);
    int hd = lane >> 4;
    float acc[8] = {0.f, 0.f, 0.f, 0.f, 0.f, 0.f, 0.f, 0.f};

    // pipelined weighted aggregate over one LDS chunk of (src, alpha) pairs
    auto chunk_aggr = [&](int cnt) {
        int s_cur = s_sh[w][0];
        float al_cur = al_sh[w][0][hd];
        uint4 hv = *(const uint4*)(hbf + s_cur * 512 + lane * 8);
        for (int i = 0; i < cnt; i++) {
            int s_nxt = s_sh[w][i + 1];          // sentinel slot makes this always safe
            float al_nxt = al_sh[w][i + 1][hd];
            uint4 hv_n = *(const uint4*)(hbf + s_nxt * 512 + lane * 8);
            u32 h0 = hv.x, h1 = hv.y, h2 = hv.z, h3 = hv.w;
            acc[0] += al_cur * __uint_as_float(h0 << 16);
            acc[1] += al_cur * __uint_as_float(h0 & 0xffff0000u);
            acc[2] += al_cur * __uint_as_float(h1 << 16);
            acc[3] += al_cur * __uint_as_float(h1 & 0xffff0000u);
            acc[4] += al_cur * __uint_as_float(h2 << 16);
            acc[5] += al_cur * __uint_as_float(h2 & 0xffff0000u);
            acc[6] += al_cur * __uint_as_float(h3 << 16);
            acc[7] += al_cur * __uint_as_float(h3 & 0xffff0000u);
            hv = hv_n;
            al_cur = al_nxt;
        }
    };

    if (deg <= 64) {
        // ---- fast path: one lane per edge, e kept in registers across passes ----
        int j = start + lane;
        int s = 0;
        f32x4 e = {-1e30f, -1e30f, -1e30f, -1e30f};
        if (j < end) {
            s = esrc[j];
            f32x4 as = *(const f32x4*)(a_s + s * 4);
            for (int c = 0; c < 4; c++) {
                float v = as[c] + ad[c];
                e[c] = v > 0.f ? v : NEG_SLOPE * v;
            }
        }
        f32x4 mx = e;
        for (int off = 32; off; off >>= 1)
            for (int c = 0; c < 4; c++) mx[c] = fmaxf(mx[c], __shfl_xor(mx[c], off));
        f32x4 p;
        for (int c = 0; c < 4; c++) p[c] = __expf(e[c] - mx[c]);  // invalid lanes -> 0
        f32x4 den = p;
        for (int off = 32; off; off >>= 1)
            for (int c = 0; c < 4; c++) den[c] += __shfl_xor(den[c], off);
        f32x4 alpha;
        for (int c = 0; c < 4; c++) alpha[c] = p[c] * (1.f / den[c]);
        s_sh[w][lane] = s;
        *(f32x4*)&al_sh[w][lane][0] = alpha;
        if (lane == 63) {  // sentinel for the deg==64 prefetch
            s_sh[w][64] = 0;
            f32x4 z = {0.f, 0.f, 0.f, 0.f};
            *(f32x4*)&al_sh[w][64][0] = z;
        }
        __builtin_amdgcn_wave_barrier();
        chunk_aggr(deg);
    } else {
        // ---- general path (deg > 64): strided softmax passes, chunked aggregate ----
        f32x4 mx = {-1e30f, -1e30f, -1e30f, -1e30f};
        for (int j = start + lane; j < end; j += 64) {
            int s = esrc[j];
            f32x4 e = *(const f32x4*)(a_s + s * 4) + ad;
            for (int c = 0; c < 4; c++) {
                float v = e[c];
                v = v > 0.f ? v : NEG_SLOPE * v;
                mx[c] = fmaxf(mx[c], v);
            }
        }
        for (int off = 32; off; off >>= 1)
            for (int c = 0; c < 4; c++) mx[c] = fmaxf(mx[c], __shfl_xor(mx[c], off));
        f32x4 den = {0.f, 0.f, 0.f, 0.f};
        for (int j = start + lane; j < end; j += 64) {
            int s = esrc[j];
            f32x4 e = *(const f32x4*)(a_s + s * 4) + ad;
            for (int c = 0; c < 4; c++) {
                float v = e[c];
                v = v > 0.f ? v : NEG_SLOPE * v;
                den[c] += __expf(v - mx[c]);
            }
        }
        for (int off = 32; off; off >>= 1)
            for (int c = 0; c < 4; c++) den[c] += __shfl_xor(den[c], off);
        f32x4 rd;
        for (int c = 0; c < 4; c++) rd[c] = 1.f / den[c];
        for (int base = start; base < end; base += 64) {
            int cnt = min(64, end - base);
            int jj = base + lane;
            int s = 0;
            f32x4 alpha = {0.f, 0.f, 0.f, 0.f};
            if (jj < end) {
                s = esrc[jj];
                f32x4 e = *(const f32x4*)(a_s + s * 4) + ad;
                for (int c = 0; c < 4; c++) {
                    float v = e[c];
                    v = v > 0.f ? v : NEG_SLOPE * v;
                    alpha[c] = __expf(v - mx[c]) * rd[c];
                }
            }
            s_sh[w][lane] = s;
            *(f32x4*)&al_sh[w][lane][0] = alpha;
            if (lane == 63) {
                s_sh[w][64] = 0;
                f32x4 z = {0.f, 0.f, 0.f, 0.f};
                *(f32x4*)&al_sh[w][64][0] = z;
            }
            __builtin_amdgcn_wave_barrier();
            chunk_aggr(cnt);
            __builtin_amdgcn_wave_barrier();
        }
    }

    // epilogue: +bias, elu, mean-of-4-consecutive (head-major -> out chan), recurrence
    f32x4 b0 = *(const f32x4*)(bias + lane * 8);
    f32x4 b1 = *(const f32x4*)(bias + lane * 8 + 4);
    float g[8];
    for (int i = 0; i < 4; i++) g[i] = acc[i] + b0[i];
    for (int i = 0; i < 4; i++) g[4 + i] = acc[4 + i] + b1[i];
    for (int i = 0; i < 8; i++) {
        float v = g[i];
        g[i] = v > 0.f ? v : __expf(v) - 1.f;
    }
    float agg0 = (g[0] + g[1] + g[2] + g[3]) * 0.25f;  // out channel lane*2
    float agg1 = (g[4] + g[5] + g[6] + g[7]) * 0.25f;  // out channel lane*2+1
    int i0 = lane * 2;
    int xo = d * LSTRIDE + layer * 128 + i0;
    int no = d * LSTRIDE + (layer + 1) * 128 + i0;
    float x0 = Xall[xo], x1 = Xall[xo + 1];
    Xall[no] = agg0;          // X2 = agg
    Xall[no + 1] = agg1;
    Yall[no] = agg0 - x0;     // Y2 = agg - X_prev
    Yall[no + 1] = agg1 - x1;
    Xbf[d * 128 + i0] = f2bf(agg0);
    Xbf[d * 128 + i0 + 1] = f2bf(agg1);

    // fused attention logits for the NEXT layer (written to double-buffer)
    f32x4 vs0 = *(const f32x4*)(Vs + i0 * 4), vs1 = *(const f32x4*)(Vs + (i0 + 1) * 4);
    f32x4 vd0 = *(const f32x4*)(Vd + i0 * 4), vd1 = *(const f32x4*)(Vd + (i0 + 1) * 4);
    f32x4 ps, pd;
    for (int c = 0; c < 4; c++) {
        ps[c] = agg0 * vs0[c] + agg1 * vs1[c];
        pd[c] = agg0 * vd0[c] + agg1 * vd1[c];
    }
    for (int off = 32; off; off >>= 1)
        for (int c = 0; c < 4; c++) {
            ps[c] += __shfl_xor(ps[c], off);
            pd[c] += __shfl_xor(pd[c], off);
        }
    if (lane == 0) {
        *(f32x4*)(a_s_nxt + d * 4) = ps;
        *(f32x4*)(a_d_nxt + d * 4) = pd;
    }
}

// ---------------- readout: out[N][40] = X_final @ Wr^T + br ----------------
__global__ __launch_bounds__(256) void k_out(const float* __restrict__ Xall,
                                             const float* __restrict__ Wr,
                                             const float* __restrict__ br,
                                             float* __restrict__ out) {
    __shared__ float Xs[4][128];
    int wave = threadIdx.x >> 6, lane = threadIdx.x & 63;
    int n = blockIdx.x * 4 + wave;  // grid exact: 5000 blocks
    const float* Xr = Xall + n * LSTRIDE + NLAYERS * 128;
    Xs[wave][lane] = Xr[lane];
    Xs[wave][64 + lane] = Xr[64 + lane];
    __syncthreads();
    if (lane < NCLASS) {
        float acc = 0.f;
        for (int kc = 0; kc < 32; kc++) {
            f32x4 wv = *(const f32x4*)(Wr + lane * 128 + kc * 4);
            for (int q = 0; q < 4; q++) acc += Xs[wave][kc * 4 + q] * wv[q];
        }
        out[n * NCLASS + lane] = acc + br[lane];
    }
}

extern "C" void kernel_launch(void* const* d_in, const int* in_sizes, int n_in,
                              void* d_out, int out_size, void* d_ws, size_t ws_size,
                              hipStream_t stream) {
    const float* x = (const float*)d_in[0];
    const int* src = (const int*)d_in[1];
    const int* dst = (const int*)d_in[2];
    const float* W = (const float*)d_in[3];
    const float* att_s = (const float*)d_in[4];
    const float* att_d = (const float*)d_in[5];
    const float* bias = (const float*)d_in[6];
    const float* Wr = (const float*)d_in[7];
    const float* br = (const float*)d_in[8];

    float* out = (float*)d_out;
    float* Xall = out + (size_t)N_NODES * NCLASS;
    float* Yall = Xall + (size_t)N_NODES * LSTRIDE;

    char* p = (char*)d_ws;
    auto alloc = [&](size_t bytes) -> char* {
        char* r = p;
        p += (bytes + 255) & ~(size_t)255;
        return r;
    };
    u16* Xbf = (u16*)alloc((size_t)N_NODES * 128 * 2);
    u16* hbf = (u16*)alloc((size_t)N_NODES * 512 * 2);
    u16* Wt = (u16*)alloc(512 * 128 * 2);
    float* a_sA = (float*)alloc((size_t)N_NODES * 4 * 4);
    float* a_dA = (float*)alloc((size_t)N_NODES * 4 * 4);
    float* a_sB = (float*)alloc((size_t)N_NODES * 4 * 4);
    float* a_dB = (float*)alloc((size_t)N_NODES * 4 * 4);
    float* Vs = (float*)alloc(128 * 4 * 4);
    float* Vd = (float*)alloc(128 * 4 * 4);
    int* indptr = (int*)alloc((N_NODES + 1) * 4);
    int* cursor = (int*)alloc(N_NODES * 4);
    int* counts = (int*)alloc(N_NODES * 4);
    int* esrc = (int*)alloc((size_t)(NE + N_NODES) * 4);

    k_init<<<(N_NODES * 128 + 255) / 256, 256, 0, stream>>>(x, Xbf, Xall, Yall);
    k_trans<<<(512 * 128) / 256, 256, 0, stream>>>(W, Wt);
    k_fold<<<128, 256, 0, stream>>>(W, att_s, att_d, Vs, Vd);
    k_ones<<<(N_NODES + 255) / 256, 256, 0, stream>>>(counts);
    k_count<<<(NE + 255) / 256, 256, 0, stream>>>(dst, counts);
    k_scan<<<1, 1024, 0, stream>>>(counts, indptr, cursor);
    k_scatter<<<(NE + N_NODES + 255) / 256, 256, 0, stream>>>(src, dst, cursor, esrc);

    // layer-0 logits from initial X; subsequent layers are produced by k_aggr's epilogue
    k_att<<<N_NODES / 4, 256, 0, stream>>>(Xall, 0, Vs, Vd, a_sA, a_dA);

    for (int layer = 0; layer < NLAYERS; layer++) {
        const float* as_r = (layer & 1) ? a_sB : a_sA;
        const float* ad_r = (layer & 1) ? a_dB : a_dA;
        float* as_w = (layer & 1) ? a_sA : a_sB;
        float* ad_w = (layer & 1) ? a_dA : a_dB;
        k_gemm<<<dim3((N_NODES + 63) / 64, 8), 256, 0, stream>>>(Xbf, Wt, hbf);
        k_aggr<<<N_NODES / 4, 256, 0, stream>>>(indptr, esrc, as_r, ad_r, hbf, bias,
                                                Xbf, Xall, Yall, as_w, ad_w, Vs, Vd, layer);
    }
    k_out<<<N_NODES / 4, 256, 0, stream>>>(Xall, Wr, br, out);
}

// Round 3
// 500.786 us; speedup vs baseline: 1.2467x; 1.0610x over previous
//
#include <hip/hip_runtime.h>

typedef unsigned short u16;
typedef unsigned int u32;

#define N_NODES 20000
#define NE 320000
#define NLAYERS 4
#define NCLASS 40
#define NEG_SLOPE 0.2f
#define LSTRIDE ((NLAYERS + 1) * 128)  // 640 floats per node in X_all/Y_all

typedef __bf16 bf16x8 __attribute__((ext_vector_type(8)));
typedef float f32x4 __attribute__((ext_vector_type(4)));

__device__ inline u16 f2bf(float f) {
    u32 u = __float_as_uint(f);
    return (u16)((u + 0x7fffu + ((u >> 16) & 1u)) >> 16);  // round-nearest-even
}
__device__ inline float bf2f(u16 u) { return __uint_as_float(((u32)u) << 16); }

// ---------------- init: Xbf=bf16(x), X_all[:,0,:]=x, Y_all[:,0,:]=x, counts=1 ----------------
__global__ void k_init(const float* __restrict__ x, u16* __restrict__ Xbf,
                       float* __restrict__ Xall, float* __restrict__ Yall,
                       int* __restrict__ counts) {
    int t = blockIdx.x * 256 + threadIdx.x;
    if (t >= N_NODES * 128) return;
    if (t < N_NODES) counts[t] = 1;  // self loop seed for CSR
    float v = x[t];
    Xbf[t] = f2bf(v);
    int n = t >> 7, c = t & 127;
    int ob = n * LSTRIDE + c;  // layer-0 slot
    Xall[ob] = v;
    Yall[ob] = v;
}

// ---------------- Wt[512][128] = bf16(W^T) ----------------
__global__ void k_trans(const float* __restrict__ W, u16* __restrict__ Wt) {
    int t = blockIdx.x * 256 + threadIdx.x;  // 65536 threads
    int k = t >> 9, col = t & 511;
    Wt[col * 128 + k] = f2bf(W[t]);
}

// ---------------- fold attention vectors through W: Vs/Vd[128][4] (f32, exact path) ----
__global__ __launch_bounds__(256) void k_fold(const float* __restrict__ W,
                                              const float* __restrict__ att_s,
                                              const float* __restrict__ att_d,
                                              float* __restrict__ Vs, float* __restrict__ Vd) {
    int wid = (blockIdx.x * 256 + threadIdx.x) >> 6;  // 0..511 = t*4+hd
    int lane = threadIdx.x & 63;
    int t = wid >> 2, hd = wid & 3;
    float w0 = W[t * 512 + hd * 128 + lane];
    float w1 = W[t * 512 + hd * 128 + 64 + lane];
    float s1 = w0 * att_s[hd * 128 + lane] + w1 * att_s[hd * 128 + 64 + lane];
    float s2 = w0 * att_d[hd * 128 + lane] + w1 * att_d[hd * 128 + 64 + lane];
    for (int off = 32; off; off >>= 1) {
        s1 += __shfl_xor(s1, off);
        s2 += __shfl_xor(s2, off);
    }
    if (lane == 0) {
        Vs[t * 4 + hd] = s1;
        Vd[t * 4 + hd] = s2;
    }
}

// ---------------- CSR build over dst (self loops included) ----------------
__global__ void k_count(const int* __restrict__ dst, int* __restrict__ counts) {
    int t = blockIdx.x * 256 + threadIdx.x;
    if (t < NE) atomicAdd(&counts[dst[t]], 1);
}
__global__ void k_scan(const int* __restrict__ counts, int* __restrict__ indptr,
                       int* __restrict__ cursor) {
    __shared__ int part[1024];
    int t = threadIdx.x;
    const int CH = 20;  // 1024*20 >= 20000
    int c0 = t * CH;
    int s = 0;
    for (int i = 0; i < CH; i++) {
        int idx = c0 + i;
        if (idx < N_NODES) s += counts[idx];
    }
    part[t] = s;
    __syncthreads();
    for (int off = 1; off < 1024; off <<= 1) {
        int v = 0;
        if (t >= off) v = part[t - off];
        __syncthreads();
        if (t >= off) part[t] += v;
        __syncthreads();
    }
    int ex = (t == 0) ? 0 : part[t - 1];
    for (int i = 0; i < CH; i++) {
        int idx = c0 + i;
        if (idx < N_NODES) {
            indptr[idx] = ex;
            cursor[idx] = ex;
            ex += counts[idx];
        }
    }
    if (t == 1023) indptr[N_NODES] = part[1023];
}
__global__ void k_scatter(const int* __restrict__ src, const int* __restrict__ dst,
                          int* __restrict__ cursor, int* __restrict__ esrc) {
    int t = blockIdx.x * 256 + threadIdx.x;
    if (t >= NE + N_NODES) return;
    int s, d;
    if (t < NE) { s = src[t]; d = dst[t]; }
    else { s = d = t - NE; }
    int pos = atomicAdd(&cursor[d], 1);
    esrc[pos] = s;
}

// ---------------- attention logits for layer 0: a_s/a_d[N][4] = X @ Vs/Vd ----------------
__global__ __launch_bounds__(256) void k_att(const float* __restrict__ Xall, int layer,
                                             const float* __restrict__ Vs,
                                             const float* __restrict__ Vd,
                                             float* __restrict__ a_s, float* __restrict__ a_d) {
    int wid = (blockIdx.x * 256 + threadIdx.x) >> 6;  // node, grid exact
    int lane = threadIdx.x & 63;
    const float* Xr = Xall + wid * LSTRIDE + layer * 128;
    float x0 = Xr[lane], x1 = Xr[64 + lane];
    f32x4 vs0 = *(const f32x4*)(Vs + lane * 4), vs1 = *(const f32x4*)(Vs + (64 + lane) * 4);
    f32x4 vd0 = *(const f32x4*)(Vd + lane * 4), vd1 = *(const f32x4*)(Vd + (64 + lane) * 4);
    f32x4 ps = x0 * vs0 + x1 * vs1;
    f32x4 pd = x0 * vd0 + x1 * vd1;
    for (int off = 32; off; off >>= 1)
        for (int c = 0; c < 4; c++) {
            ps[c] += __shfl_xor(ps[c], off);
            pd[c] += __shfl_xor(pd[c], off);
        }
    if (lane == 0) {
        *(f32x4*)(a_s + wid * 4) = ps;
        *(f32x4*)(a_d + wid * 4) = pd;
    }
}

// ---------------- per-dst-node: softmax + per-head weighted X-gather -> Xagg[d][h*128+k] ----
// out[d,h,:] = (sum_e alpha_e^h X[src_e]) @ W_h  -- aggregation commutes with the GEMM,
// so gather 128 bf16 channels (256B/edge) instead of 512 (1KB/edge); Xbf (5MB) is ~L2-resident.
__global__ __launch_bounds__(256) void k_aggr(
    const int* __restrict__ indptr, const int* __restrict__ esrc,
    const float* __restrict__ a_s, const float* __restrict__ a_d,
    const u16* __restrict__ Xbf, u16* __restrict__ Xagg) {
    __shared__ int s_sh[4][66];
    __shared__ alignas(16) float al_sh[4][66][4];
    int d = (blockIdx.x * 256 + threadIdx.x) >> 6;  // grid exact: 5000 blocks -> 20000 waves
    int lane = threadIdx.x & 63;
    int w = threadIdx.x >> 6;
    int start = indptr[d], end = indptr[d + 1];
    int deg = end - start;
    f32x4 ad = *(const f32x4*)(a_d + d * 4);
    f32x4 accA = {0.f, 0.f, 0.f, 0.f};  // heads for channel lane*2
    f32x4 accB = {0.f, 0.f, 0.f, 0.f};  // heads for channel lane*2+1

    // pipelined weighted aggregate over one LDS chunk of (src, alpha[4]) pairs
    auto chunk_aggr = [&](int cnt) {
        int s_cur = s_sh[w][0];
        f32x4 al_cur = *(const f32x4*)&al_sh[w][0][0];
        u32 xv = *(const u32*)(Xbf + s_cur * 128 + lane * 2);
        for (int i = 0; i < cnt; i++) {
            int s_nxt = s_sh[w][i + 1];  // sentinel slot makes this always safe
            f32x4 al_nxt = *(const f32x4*)&al_sh[w][i + 1][0];
            u32 xv_n = *(const u32*)(Xbf + s_nxt * 128 + lane * 2);
            float x0 = __uint_as_float(xv << 16);
            float x1 = __uint_as_float(xv & 0xffff0000u);
            accA += al_cur * x0;
            accB += al_cur * x1;
            xv = xv_n;
            al_cur = al_nxt;
        }
    };

    if (deg <= 64) {
        // ---- fast path: one lane per edge, e kept in registers across passes ----
        int j = start + lane;
        int s = 0;
        f32x4 e = {-1e30f, -1e30f, -1e30f, -1e30f};
        if (j < end) {
            s = esrc[j];
            f32x4 as = *(const f32x4*)(a_s + s * 4);
            for (int c = 0; c < 4; c++) {
                float v = as[c] + ad[c];
                e[c] = v > 0.f ? v : NEG_SLOPE * v;
            }
        }
        f32x4 mx = e;
        for (int off = 32; off; off >>= 1)
            for (int c = 0; c < 4; c++) mx[c] = fmaxf(mx[c], __shfl_xor(mx[c], off));
        f32x4 p;
        for (int c = 0; c < 4; c++) p[c] = __expf(e[c] - mx[c]);  // invalid lanes -> 0
        f32x4 den = p;
        for (int off = 32; off; off >>= 1)
            for (int c = 0; c < 4; c++) den[c] += __shfl_xor(den[c], off);
        f32x4 alpha;
        for (int c = 0; c < 4; c++) alpha[c] = p[c] * (1.f / den[c]);
        s_sh[w][lane] = s;
        *(f32x4*)&al_sh[w][lane][0] = alpha;
        if (lane == 63) {  // sentinel for the deg==64 prefetch
            s_sh[w][64] = 0;
            f32x4 z = {0.f, 0.f, 0.f, 0.f};
            *(f32x4*)&al_sh[w][64][0] = z;
        }
        __builtin_amdgcn_wave_barrier();
        chunk_aggr(deg);
    } else {
        // ---- general path (deg > 64): strided softmax passes, chunked aggregate ----
        f32x4 mx = {-1e30f, -1e30f, -1e30f, -1e30f};
        for (int j = start + lane; j < end; j += 64) {
            int s = esrc[j];
            f32x4 e = *(const f32x4*)(a_s + s * 4) + ad;
            for (int c = 0; c < 4; c++) {
                float v = e[c];
                v = v > 0.f ? v : NEG_SLOPE * v;
                mx[c] = fmaxf(mx[c], v);
            }
        }
        for (int off = 32; off; off >>= 1)
            for (int c = 0; c < 4; c++) mx[c] = fmaxf(mx[c], __shfl_xor(mx[c], off));
        f32x4 den = {0.f, 0.f, 0.f, 0.f};
        for (int j = start + lane; j < end; j += 64) {
            int s = esrc[j];
            f32x4 e = *(const f32x4*)(a_s + s * 4) + ad;
            for (int c = 0; c < 4; c++) {
                float v = e[c];
                v = v > 0.f ? v : NEG_SLOPE * v;
                den[c] += __expf(v - mx[c]);
            }
        }
        for (int off = 32; off; off >>= 1)
            for (int c = 0; c < 4; c++) den[c] += __shfl_xor(den[c], off);
        f32x4 rd;
        for (int c = 0; c < 4; c++) rd[c] = 1.f / den[c];
        for (int base = start; base < end; base += 64) {
            int cnt = min(64, end - base);
            int jj = base + lane;
            int s = 0;
            f32x4 alpha = {0.f, 0.f, 0.f, 0.f};
            if (jj < end) {
                s = esrc[jj];
                f32x4 e = *(const f32x4*)(a_s + s * 4) + ad;
                for (int c = 0; c < 4; c++) {
                    float v = e[c];
                    v = v > 0.f ? v : NEG_SLOPE * v;
                    alpha[c] = __expf(v - mx[c]) * rd[c];
                }
            }
            s_sh[w][lane] = s;
            *(f32x4*)&al_sh[w][lane][0] = alpha;
            if (lane == 63) {
                s_sh[w][64] = 0;
                f32x4 z = {0.f, 0.f, 0.f, 0.f};
                *(f32x4*)&al_sh[w][64][0] = z;
            }
            __builtin_amdgcn_wave_barrier();
            chunk_aggr(cnt);
            __builtin_amdgcn_wave_barrier();
        }
    }

    // store Xagg[d][h*128 + lane*2 + {0,1}] as packed bf16 pairs (coalesced dword stores)
    u16* xo = Xagg + d * 512 + lane * 2;
    for (int hh = 0; hh < 4; hh++) {
        u32 pk = (u32)f2bf(accA[hh]) | ((u32)f2bf(accB[hh]) << 16);
        *(u32*)(xo + hh * 128) = pk;
    }
}

// ---------------- fused per-head GEMM + bias + elu + 4-consecutive-mean + recurrence + logits ----
// block: 16 nodes x 512 out-ch, 8 waves; wave w: head w>>1, col-half w&1 (64 cols).
// NOTE: reference's .reshape(N,NHID,HEADS).mean(-1) on the HEAD-MAJOR flat [H*C] array means
// out channel i = mean(flat[4i..4i+3]) = 4 consecutive channels of head i>>5 -- NOT a head mean.
__global__ __launch_bounds__(512) void k_fuse(
    const u16* __restrict__ Xagg, const u16* __restrict__ Wt,
    const float* __restrict__ bias,
    float* __restrict__ Xall, float* __restrict__ Yall, u16* __restrict__ Xbf,
    float* __restrict__ a_s_nxt, float* __restrict__ a_d_nxt,
    const float* __restrict__ Vs, const float* __restrict__ Vd,
    int layer, int do_logits) {
    __shared__ u16 As[16 * 520];        // 16 rows x 512 + 8 pad
    __shared__ float G[16 * 528];       // elu(out+bias), flat head-major: row*528 + h*128 + ch
    __shared__ float aggbuf[16 * 130];  // mean result for logits phase
    const int t = threadIdx.x;
    const int r0 = blockIdx.x * 16;     // 1250 blocks exact
    const int wv = t >> 6, lane = t & 63;
    const int h = wv >> 1, colhalf = wv & 1;
    const int lrow = lane & 15, quad = lane >> 4;

    // preload B fragments straight from global (Wt is 128KB, L2-hot)
    bf16x8 bfr[16];
    {
        const u16* Wb = Wt + (h * 128 + colhalf * 64) * 128;
        for (int k4 = 0; k4 < 4; k4++)
            for (int ni = 0; ni < 4; ni++)
                bfr[k4 * 4 + ni] =
                    *(const bf16x8*)(Wb + (ni * 16 + lrow) * 128 + k4 * 32 + quad * 8);
    }
    // stage A (Xagg rows, sequential/coalesced)
    for (int i = 0; i < 2; i++) {
        int flat = i * 512 + t;
        int row = flat >> 6, kc = flat & 63;
        *(uint4*)(As + row * 520 + kc * 8) = *(const uint4*)(Xagg + (r0 + row) * 512 + kc * 8);
    }
    __syncthreads();
    f32x4 acc[4] = {};
    for (int k4 = 0; k4 < 4; k4++) {
        bf16x8 a = *(const bf16x8*)(As + lrow * 520 + h * 128 + k4 * 32 + quad * 8);
        for (int ni = 0; ni < 4; ni++)
            acc[ni] = __builtin_amdgcn_mfma_f32_16x16x32_bf16(a, bfr[k4 * 4 + ni], acc[ni], 0, 0, 0);
    }
    // bias + elu into G (f32, flat head-major per row)
    for (int ni = 0; ni < 4; ni++) {
        int c = colhalf * 64 + ni * 16 + lrow;  // within-head channel
        float bv = bias[h * 128 + c];
        for (int r = 0; r < 4; r++) {
            float v = acc[ni][r] + bv;
            v = v > 0.f ? v : __expf(v) - 1.f;
            G[(quad * 4 + r) * 528 + h * 128 + c] = v;
        }
    }
    __syncthreads();
    // 4-consecutive mean (head-major) + recurrence; thread t: out chan c = t&127, row group t>>7
    {
        int c = t & 127, rg = t >> 7;
        int hh = c >> 5, cc = (c & 31) * 4;  // head, base within-head channel
        for (int rr = 0; rr < 4; rr++) {
            int row = rg * 4 + rr;
            f32x4 gp = *(const f32x4*)&G[row * 528 + hh * 128 + cc];
            float agg = 0.25f * (gp[0] + gp[1] + gp[2] + gp[3]);
            aggbuf[row * 130 + c] = agg;
            int node = r0 + row;
            int xo = node * LSTRIDE + layer * 128 + c;
            int no = node * LSTRIDE + (layer + 1) * 128 + c;
            float xp = Xall[xo];
            Xall[no] = agg;           // X2 = agg
            Yall[no] = agg - xp;      // Y2 = agg - X_prev
            Xbf[node * 128 + c] = f2bf(agg);
        }
    }
    if (do_logits) {
        __syncthreads();
        f32x4 vs0 = *(const f32x4*)(Vs + lane * 4), vs1 = *(const f32x4*)(Vs + (64 + lane) * 4);
        f32x4 vd0 = *(const f32x4*)(Vd + lane * 4), vd1 = *(const f32x4*)(Vd + (64 + lane) * 4);
        for (int rr = 0; rr < 2; rr++) {
            int row = wv * 2 + rr;
            float x0 = aggbuf[row * 130 + lane], x1 = aggbuf[row * 130 + 64 + lane];
            f32x4 ps = x0 * vs0 + x1 * vs1;
            f32x4 pd = x0 * vd0 + x1 * vd1;
            for (int off = 32; off; off >>= 1)
                for (int c2 = 0; c2 < 4; c2++) {
                    ps[c2] += __shfl_xor(ps[c2], off);
                    pd[c2] += __shfl_xor(pd[c2], off);
                }
            if (lane == 0) {
                int node = r0 + row;
                *(f32x4*)(a_s_nxt + node * 4) = ps;
                *(f32x4*)(a_d_nxt + node * 4) = pd;
            }
        }
    }
}

// ---------------- readout: out[N][40] = X_final @ Wr^T + br ----------------
__global__ __launch_bounds__(256) void k_out(const float* __restrict__ Xall,
                                             const float* __restrict__ Wr,
                                             const float* __restrict__ br,
                                             float* __restrict__ out) {
    __shared__ float Xs[4][128];
    int wave = threadIdx.x >> 6, lane = threadIdx.x & 63;
    int n = blockIdx.x * 4 + wave;  // grid exact: 5000 blocks
    const float* Xr = Xall + n * LSTRIDE + NLAYERS * 128;
    Xs[wave][lane] = Xr[lane];
    Xs[wave][64 + lane] = Xr[64 + lane];
    __syncthreads();
    if (lane < NCLASS) {
        float acc = 0.f;
        for (int kc = 0; kc < 32; kc++) {
            f32x4 wv = *(const f32x4*)(Wr + lane * 128 + kc * 4);
            for (int q = 0; q < 4; q++) acc += Xs[wave][kc * 4 + q] * wv[q];
        }
        out[n * NCLASS + lane] = acc + br[lane];
    }
}

extern "C" void kernel_launch(void* const* d_in, const int* in_sizes, int n_in,
                              void* d_out, int out_size, void* d_ws, size_t ws_size,
                              hipStream_t stream) {
    const float* x = (const float*)d_in[0];
    const int* src = (const int*)d_in[1];
    const int* dst = (const int*)d_in[2];
    const float* W = (const float*)d_in[3];
    const float* att_s = (const float*)d_in[4];
    const float* att_d = (const float*)d_in[5];
    const float* bias = (const float*)d_in[6];
    const float* Wr = (const float*)d_in[7];
    const float* br = (const float*)d_in[8];

    float* out = (float*)d_out;
    float* Xall = out + (size_t)N_NODES * NCLASS;
    float* Yall = Xall + (size_t)N_NODES * LSTRIDE;

    char* p = (char*)d_ws;
    auto alloc = [&](size_t bytes) -> char* {
        char* r = p;
        p += (bytes + 255) & ~(size_t)255;
        return r;
    };
    u16* Xbf = (u16*)alloc((size_t)N_NODES * 128 * 2);
    u16* Xagg = (u16*)alloc((size_t)N_NODES * 512 * 2);
    u16* Wt = (u16*)alloc(512 * 128 * 2);
    float* a_sA = (float*)alloc((size_t)N_NODES * 4 * 4);
    float* a_dA = (float*)alloc((size_t)N_NODES * 4 * 4);
    float* a_sB = (float*)alloc((size_t)N_NODES * 4 * 4);
    float* a_dB = (float*)alloc((size_t)N_NODES * 4 * 4);
    float* Vs = (float*)alloc(128 * 4 * 4);
    float* Vd = (float*)alloc(128 * 4 * 4);
    int* indptr = (int*)alloc((N_NODES + 1) * 4);
    int* cursor = (int*)alloc(N_NODES * 4);
    int* counts = (int*)alloc(N_NODES * 4);
    int* esrc = (int*)alloc((size_t)(NE + N_NODES) * 4);

    k_init<<<(N_NODES * 128 + 255) / 256, 256, 0, stream>>>(x, Xbf, Xall, Yall, counts);
    k_trans<<<(512 * 128) / 256, 256, 0, stream>>>(W, Wt);
    k_fold<<<128, 256, 0, stream>>>(W, att_s, att_d, Vs, Vd);
    k_count<<<(NE + 255) / 256, 256, 0, stream>>>(dst, counts);
    k_scan<<<1, 1024, 0, stream>>>(counts, indptr, cursor);
    k_scatter<<<(NE + N_NODES + 255) / 256, 256, 0, stream>>>(src, dst, cursor, esrc);

    // layer-0 logits from initial X; subsequent layers come from k_fuse's epilogue
    k_att<<<N_NODES / 4, 256, 0, stream>>>(Xall, 0, Vs, Vd, a_sA, a_dA);

    for (int layer = 0; layer < NLAYERS; layer++) {
        const float* as_r = (layer & 1) ? a_sB : a_sA;
        const float* ad_r = (layer & 1) ? a_dB : a_dA;
        float* as_w = (layer & 1) ? a_sA : a_sB;
        float* ad_w = (layer & 1) ? a_dA : a_dB;
        k_aggr<<<N_NODES / 4, 256, 0, stream>>>(indptr, esrc, as_r, ad_r, Xbf, Xagg);
        k_fuse<<<N_NODES / 16, 512, 0, stream>>>(Xagg, Wt, bias, Xall, Yall, Xbf,
                                                 as_w, ad_w, Vs, Vd, layer,
                                                 (layer + 1 < NLAYERS) ? 1 : 0);
    }
    k_out<<<N_NODES / 4, 256, 0, stream>>>(Xall, Wr, br, out);
}

// Round 4
// 478.092 us; speedup vs baseline: 1.3059x; 1.0475x over previous
//
#include <hip/hip_runtime.h>

typedef unsigned short u16;
typedef unsigned int u32;

#define N_NODES 20000
#define NE 320000
#define NLAYERS 4
#define NCLASS 40
#define NEG_SLOPE 0.2f
#define LSTRIDE ((NLAYERS + 1) * 128)  // 640 floats per node in X_all/Y_all

typedef __bf16 bf16x8 __attribute__((ext_vector_type(8)));
typedef float f32x4 __attribute__((ext_vector_type(4)));

__device__ inline u16 f2bf(float f) {
    u32 u = __float_as_uint(f);
    return (u16)((u + 0x7fffu + ((u >> 16) & 1u)) >> 16);  // round-nearest-even
}
__device__ inline u32 pack2bf(float lo, float hi) {
    return (u32)f2bf(lo) | ((u32)f2bf(hi) << 16);
}

// ================= pre1: init + W-transpose + att-fold + degree-count (block-partitioned) ====
#define P1_INIT 10000
#define P1_TRANS 256
#define P1_FOLD 128
#define P1_COUNT 1250
__global__ __launch_bounds__(256) void k_pre1(
    const float* __restrict__ x, const int* __restrict__ dst,
    const float* __restrict__ W, const float* __restrict__ att_s,
    const float* __restrict__ att_d,
    u16* __restrict__ Xbf, float* __restrict__ Xall, float* __restrict__ Yall,
    u16* __restrict__ Wt, float* __restrict__ Vs, float* __restrict__ Vd,
    int* __restrict__ counts) {
    int b = blockIdx.x;
    if (b < P1_INIT) {
        // init: Xbf=bf16(x), X_all[:,0,:]=x, Y_all[:,0,:]=x  (10000*256 == N*128 exact)
        int t = b * 256 + threadIdx.x;
        float v = x[t];
        Xbf[t] = f2bf(v);
        int n = t >> 7, c = t & 127;
        int ob = n * LSTRIDE + c;
        Xall[ob] = v;
        Yall[ob] = v;
    } else if (b < P1_INIT + P1_TRANS) {
        // trans: Wt[512][128] = bf16(W^T)
        int t = (b - P1_INIT) * 256 + threadIdx.x;
        int k = t >> 9, col = t & 511;
        Wt[col * 128 + k] = f2bf(W[t]);
    } else if (b < P1_INIT + P1_TRANS + P1_FOLD) {
        // fold: Vs/Vd[128][4] = W @ att (one wave per (row, head))
        int wid = ((b - P1_INIT - P1_TRANS) * 256 + threadIdx.x) >> 6;
        int lane = threadIdx.x & 63;
        int t = wid >> 2, hd = wid & 3;
        float w0 = W[t * 512 + hd * 128 + lane];
        float w1 = W[t * 512 + hd * 128 + 64 + lane];
        float s1 = w0 * att_s[hd * 128 + lane] + w1 * att_s[hd * 128 + 64 + lane];
        float s2 = w0 * att_d[hd * 128 + lane] + w1 * att_d[hd * 128 + 64 + lane];
        for (int off = 32; off; off >>= 1) {
            s1 += __shfl_xor(s1, off);
            s2 += __shfl_xor(s2, off);
        }
        if (lane == 0) {
            Vs[t * 4 + hd] = s1;
            Vd[t * 4 + hd] = s2;
        }
    } else {
        // count: degree histogram over dst (1250*256 == NE exact); counts pre-zeroed
        int t = (b - P1_INIT - P1_TRANS - P1_FOLD) * 256 + threadIdx.x;
        atomicAdd(&counts[dst[t]], 1);
    }
}

// ================= pre2: block 0 = CSR scan (+1 self loop baked in); blocks 1.. = layer-0 logits
__global__ __launch_bounds__(1024) void k_pre2(
    const int* __restrict__ counts, int* __restrict__ indptr, int* __restrict__ cursor,
    const float* __restrict__ x, const float* __restrict__ Vs, const float* __restrict__ Vd,
    float* __restrict__ a_s, float* __restrict__ a_d) {
    if (blockIdx.x == 0) {
        __shared__ int part[1024];
        int t = threadIdx.x;
        const int CH = 20;  // 1024*20 >= 20000
        int c0 = t * CH;
        int s = 0;
        for (int i = 0; i < CH; i++) {
            int idx = c0 + i;
            if (idx < N_NODES) s += counts[idx] + 1;  // +1 = self loop
        }
        part[t] = s;
        __syncthreads();
        for (int off = 1; off < 1024; off <<= 1) {
            int v = 0;
            if (t >= off) v = part[t - off];
            __syncthreads();
            if (t >= off) part[t] += v;
            __syncthreads();
        }
        int ex = (t == 0) ? 0 : part[t - 1];
        for (int i = 0; i < CH; i++) {
            int idx = c0 + i;
            if (idx < N_NODES) {
                indptr[idx] = ex;
                cursor[idx] = ex;
                ex += counts[idx] + 1;
            }
        }
        if (t == 1023) indptr[N_NODES] = part[1023];
    } else {
        // layer-0 attention logits straight from x: a_s/a_d[n] = x[n] @ Vs/Vd
        int wave = threadIdx.x >> 6, lane = threadIdx.x & 63;
        int n = (blockIdx.x - 1) * 16 + wave;  // 1250 blocks * 16 waves = 20000
        const float* Xr = x + n * 128;
        float x0 = Xr[lane], x1 = Xr[64 + lane];
        f32x4 vs0 = *(const f32x4*)(Vs + lane * 4), vs1 = *(const f32x4*)(Vs + (64 + lane) * 4);
        f32x4 vd0 = *(const f32x4*)(Vd + lane * 4), vd1 = *(const f32x4*)(Vd + (64 + lane) * 4);
        f32x4 ps = x0 * vs0 + x1 * vs1;
        f32x4 pd = x0 * vd0 + x1 * vd1;
        for (int off = 32; off; off >>= 1)
            for (int c = 0; c < 4; c++) {
                ps[c] += __shfl_xor(ps[c], off);
                pd[c] += __shfl_xor(pd[c], off);
            }
        if (lane == 0) {
            *(f32x4*)(a_s + n * 4) = ps;
            *(f32x4*)(a_d + n * 4) = pd;
        }
    }
}

// ================= scatter: CSR fill (edges + self loops) ==================
__global__ void k_scatter(const int* __restrict__ src, const int* __restrict__ dst,
                          int* __restrict__ cursor, int* __restrict__ esrc) {
    int t = blockIdx.x * 256 + threadIdx.x;
    if (t >= NE + N_NODES) return;
    int s, d;
    if (t < NE) { s = src[t]; d = dst[t]; }
    else { s = d = t - NE; }
    int pos = atomicAdd(&cursor[d], 1);
    esrc[pos] = s;
}

// ================= fused layer: softmax-gather (2 nodes/wave, interleaved) + MFMA GEMM
//                   + bias/elu/4-consecutive-mean + recurrence + next-layer logits ==========
// block = 512 threads (8 waves), 16 nodes; grid 1250 exact.
// out[d,h,:] = (sum_e alpha_e^h X[src_e]) @ W_h  (aggregation commutes with the GEMM)
__global__ __launch_bounds__(512) void k_layer(
    const int* __restrict__ indptr, const int* __restrict__ esrc,
    const float* __restrict__ a_s, const float* __restrict__ a_d,
    const u16* __restrict__ XbfR, const u16* __restrict__ Wt,
    const float* __restrict__ bias,
    float* __restrict__ Xall, float* __restrict__ Yall, u16* __restrict__ XbfW,
    float* __restrict__ a_s_nxt, float* __restrict__ a_d_nxt,
    const float* __restrict__ Vs, const float* __restrict__ Vd,
    int layer, int do_logits) {
    __shared__ int s_sh[8][2][66];
    __shared__ alignas(16) float al_sh[8][2][66][4];
    __shared__ u16 As[16 * 520];        // 16 node-rows x 512 (head-major) + pad
    __shared__ float aggbuf[16 * 130];  // mean result
    const int t = threadIdx.x;
    const int r0 = blockIdx.x * 16;
    const int w = t >> 6, lane = t & 63;

    // ---------------- gather phase: wave w owns nodes r0+2w, r0+2w+1 ----------------
    f32x4 acc00 = {0.f, 0.f, 0.f, 0.f}, acc01 = {0.f, 0.f, 0.f, 0.f};  // node0: ch 2l, 2l+1
    f32x4 acc10 = {0.f, 0.f, 0.f, 0.f}, acc11 = {0.f, 0.f, 0.f, 0.f};  // node1
    int d0 = r0 + w * 2;
    int st0 = indptr[d0], en0 = indptr[d0 + 1], en1 = indptr[d0 + 2];
    int st1 = en0;
    int deg0 = en0 - st0, deg1 = en1 - st1;
    f32x4 ad0 = *(const f32x4*)(a_d + d0 * 4);
    f32x4 ad1 = *(const f32x4*)(a_d + d0 * 4 + 4);

    // softmax for <=64-edge node: e kept in registers, (s, alpha[4]) to per-wave LDS
    auto prep = [&](int nd, int st, int en, f32x4 ad) {
        int j = st + lane;
        int s = 0;
        f32x4 e = {-1e30f, -1e30f, -1e30f, -1e30f};
        if (j < en) {
            s = esrc[j];
            f32x4 as = *(const f32x4*)(a_s + s * 4);
            for (int c = 0; c < 4; c++) {
                float v = as[c] + ad[c];
                e[c] = v > 0.f ? v : NEG_SLOPE * v;
            }
        }
        f32x4 mx = e;
        for (int off = 32; off; off >>= 1)
            for (int c = 0; c < 4; c++) mx[c] = fmaxf(mx[c], __shfl_xor(mx[c], off));
        f32x4 p;
        for (int c = 0; c < 4; c++) p[c] = __expf(e[c] - mx[c]);  // invalid lanes -> 0
        f32x4 den = p;
        for (int off = 32; off; off >>= 1)
            for (int c = 0; c < 4; c++) den[c] += __shfl_xor(den[c], off);
        f32x4 alpha;
        for (int c = 0; c < 4; c++) alpha[c] = p[c] * (1.f / den[c]);
        s_sh[w][nd][lane] = s;
        *(f32x4*)al_sh[w][nd][lane] = alpha;
        if (lane == 63) {
            s_sh[w][nd][64] = 0;
            f32x4 z = {0.f, 0.f, 0.f, 0.f};
            *(f32x4*)al_sh[w][nd][64] = z;
        }
    };
    // single-node pipelined aggregate over an LDS chunk
    auto chunk1 = [&](int nd, int cnt, f32x4& aL, f32x4& aH) {
        int sc = s_sh[w][nd][0];
        f32x4 al = *(const f32x4*)al_sh[w][nd][0];
        u32 xv = *(const u32*)(XbfR + sc * 128 + lane * 2);
        for (int i = 0; i < cnt; i++) {
            int sn = s_sh[w][nd][i + 1];
            f32x4 an = *(const f32x4*)al_sh[w][nd][i + 1];
            u32 xn = *(const u32*)(XbfR + sn * 128 + lane * 2);
            aL += al * __uint_as_float(xv << 16);
            aH += al * __uint_as_float(xv & 0xffff0000u);
            xv = xn;
            al = an;
        }
    };
    // general path (deg > 64): strided 3-pass softmax, chunked aggregate
    auto gen = [&](int nd, int st, int en, f32x4 ad, f32x4& aL, f32x4& aH) {
        f32x4 mx = {-1e30f, -1e30f, -1e30f, -1e30f};
        for (int j = st + lane; j < en; j += 64) {
            int s = esrc[j];
            f32x4 e = *(const f32x4*)(a_s + s * 4) + ad;
            for (int c = 0; c < 4; c++) {
                float v = e[c];
                v = v > 0.f ? v : NEG_SLOPE * v;
                mx[c] = fmaxf(mx[c], v);
            }
        }
        for (int off = 32; off; off >>= 1)
            for (int c = 0; c < 4; c++) mx[c] = fmaxf(mx[c], __shfl_xor(mx[c], off));
        f32x4 den = {0.f, 0.f, 0.f, 0.f};
        for (int j = st + lane; j < en; j += 64) {
            int s = esrc[j];
            f32x4 e = *(const f32x4*)(a_s + s * 4) + ad;
            for (int c = 0; c < 4; c++) {
                float v = e[c];
                v = v > 0.f ? v : NEG_SLOPE * v;
                den[c] += __expf(v - mx[c]);
            }
        }
        for (int off = 32; off; off >>= 1)
            for (int c = 0; c < 4; c++) den[c] += __shfl_xor(den[c], off);
        f32x4 rd;
        for (int c = 0; c < 4; c++) rd[c] = 1.f / den[c];
        for (int base = st; base < en; base += 64) {
            int cnt = min(64, en - base);
            int jj = base + lane;
            int s = 0;
            f32x4 alpha = {0.f, 0.f, 0.f, 0.f};
            if (jj < en) {
                s = esrc[jj];
                f32x4 e = *(const f32x4*)(a_s + s * 4) + ad;
                for (int c = 0; c < 4; c++) {
                    float v = e[c];
                    v = v > 0.f ? v : NEG_SLOPE * v;
                    alpha[c] = __expf(v - mx[c]) * rd[c];
                }
            }
            s_sh[w][nd][lane] = s;
            *(f32x4*)al_sh[w][nd][lane] = alpha;
            if (lane == 63) {
                s_sh[w][nd][64] = 0;
                f32x4 z = {0.f, 0.f, 0.f, 0.f};
                *(f32x4*)al_sh[w][nd][64] = z;
            }
            __builtin_amdgcn_wave_barrier();
            chunk1(nd, cnt, aL, aH);
            __builtin_amdgcn_wave_barrier();
        }
    };

    if (deg0 <= 64 && deg1 <= 64) {
        prep(0, st0, en0, ad0);
        prep(1, st1, en1, ad1);
        __builtin_amdgcn_wave_barrier();
        // interleaved dual-node pipeline: 2 independent load chains in flight
        int cm = deg0 > deg1 ? deg0 : deg1;  // extra iters of shorter node add alpha=0
        int sA = s_sh[w][0][0], sB = s_sh[w][1][0];
        f32x4 aA = *(const f32x4*)al_sh[w][0][0];
        f32x4 aB = *(const f32x4*)al_sh[w][1][0];
        u32 xA = *(const u32*)(XbfR + sA * 128 + lane * 2);
        u32 xB = *(const u32*)(XbfR + sB * 128 + lane * 2);
        for (int i = 0; i < cm; i++) {
            int sA2 = s_sh[w][0][i + 1], sB2 = s_sh[w][1][i + 1];
            f32x4 aA2 = *(const f32x4*)al_sh[w][0][i + 1];
            f32x4 aB2 = *(const f32x4*)al_sh[w][1][i + 1];
            u32 xA2 = *(const u32*)(XbfR + sA2 * 128 + lane * 2);
            u32 xB2 = *(const u32*)(XbfR + sB2 * 128 + lane * 2);
            acc00 += aA * __uint_as_float(xA << 16);
            acc01 += aA * __uint_as_float(xA & 0xffff0000u);
            acc10 += aB * __uint_as_float(xB << 16);
            acc11 += aB * __uint_as_float(xB & 0xffff0000u);
            xA = xA2; aA = aA2; xB = xB2; aB = aB2;
        }
    } else {
        gen(0, st0, en0, ad0, acc00, acc01);
        gen(1, st1, en1, ad1, acc10, acc11);
    }

    // write aggregated rows into As (head-major bf16, matches Xagg layout)
    {
        u16* a0 = As + (w * 2) * 520 + lane * 2;
        u16* a1 = As + (w * 2 + 1) * 520 + lane * 2;
        for (int h = 0; h < 4; h++) {
            *(u32*)(a0 + h * 128) = pack2bf(acc00[h], acc01[h]);
            *(u32*)(a1 + h * 128) = pack2bf(acc10[h], acc11[h]);
        }
    }
    __syncthreads();

    // ---------------- MFMA phase: wave w -> head w>>1, col-half w&1 ----------------
    const int h = w >> 1, colhalf = w & 1;
    const int lrow = lane & 15, quad = lane >> 4;
    f32x4 macc[4] = {};
    for (int k4 = 0; k4 < 4; k4++) {
        bf16x8 a = *(const bf16x8*)(As + lrow * 520 + h * 128 + k4 * 32 + quad * 8);
        for (int ni = 0; ni < 4; ni++) {
            bf16x8 bfrag = *(const bf16x8*)(Wt + (h * 128 + colhalf * 64 + ni * 16 + lrow) * 128 +
                                            k4 * 32 + quad * 8);
            macc[ni] = __builtin_amdgcn_mfma_f32_16x16x32_bf16(a, bfrag, macc[ni], 0, 0, 0);
        }
    }
    // bias + elu per element, then 4-consecutive-mean via 4-lane shuffle sum.
    // (reference: out chan i = mean(flat[4i..4i+3]) on head-major flat layout)
    for (int ni = 0; ni < 4; ni++) {
        float bv = bias[h * 128 + colhalf * 64 + ni * 16 + lrow];
        for (int r = 0; r < 4; r++) {
            float v = macc[ni][r] + bv;
            v = v > 0.f ? v : __expf(v) - 1.f;
            v += __shfl_xor(v, 1);
            v += __shfl_xor(v, 2);
            if ((lrow & 3) == 0) {
                int row = quad * 4 + r;
                int cO = h * 32 + colhalf * 16 + ni * 4 + (lrow >> 2);
                aggbuf[row * 130 + cO] = 0.25f * v;
            }
        }
    }
    __syncthreads();

    // ---------------- epilogue: recurrence (coalesced) ----------------
    {
        int c = t & 127, rg = t >> 7;  // 512 threads: 128 ch x 4 row-groups
        for (int rr = 0; rr < 4; rr++) {
            int row = rg * 4 + rr;
            float agg = aggbuf[row * 130 + c];
            int node = r0 + row;
            int xo = node * LSTRIDE + layer * 128 + c;
            float xp = Xall[xo];
            Xall[xo + 128] = agg;        // X2 = agg
            Yall[xo + 128] = agg - xp;   // Y2 = agg - X_prev
            XbfW[node * 128 + c] = f2bf(agg);
        }
    }
    // ---------------- next-layer logits ----------------
    if (do_logits) {
        f32x4 vs0 = *(const f32x4*)(Vs + lane * 4), vs1 = *(const f32x4*)(Vs + (64 + lane) * 4);
        f32x4 vd0 = *(const f32x4*)(Vd + lane * 4), vd1 = *(const f32x4*)(Vd + (64 + lane) * 4);
        for (int rr = 0; rr < 2; rr++) {
            int row = w * 2 + rr;
            float x0 = aggbuf[row * 130 + lane], x1 = aggbuf[row * 130 + 64 + lane];
            f32x4 ps = x0 * vs0 + x1 * vs1;
            f32x4 pd = x0 * vd0 + x1 * vd1;
            for (int off = 32; off; off >>= 1)
                for (int c2 = 0; c2 < 4; c2++) {
                    ps[c2] += __shfl_xor(ps[c2], off);
                    pd[c2] += __shfl_xor(pd[c2], off);
                }
            if (lane == 0) {
                int node = r0 + row;
                *(f32x4*)(a_s_nxt + node * 4) = ps;
                *(f32x4*)(a_d_nxt + node * 4) = pd;
            }
        }
    }
}

// ================= readout: out[N][40] = X_final @ Wr^T + br ==================
__global__ __launch_bounds__(256) void k_out(const float* __restrict__ Xall,
                                             const float* __restrict__ Wr,
                                             const float* __restrict__ br,
                                             float* __restrict__ out) {
    __shared__ float Xs[4][128];
    int wave = threadIdx.x >> 6, lane = threadIdx.x & 63;
    int n = blockIdx.x * 4 + wave;  // grid exact: 5000 blocks
    const float* Xr = Xall + n * LSTRIDE + NLAYERS * 128;
    Xs[wave][lane] = Xr[lane];
    Xs[wave][64 + lane] = Xr[64 + lane];
    __syncthreads();
    if (lane < NCLASS) {
        float acc = 0.f;
        for (int kc = 0; kc < 32; kc++) {
            f32x4 wv = *(const f32x4*)(Wr + lane * 128 + kc * 4);
            for (int q = 0; q < 4; q++) acc += Xs[wave][kc * 4 + q] * wv[q];
        }
        out[n * NCLASS + lane] = acc + br[lane];
    }
}

extern "C" void kernel_launch(void* const* d_in, const int* in_sizes, int n_in,
                              void* d_out, int out_size, void* d_ws, size_t ws_size,
                              hipStream_t stream) {
    const float* x = (const float*)d_in[0];
    const int* src = (const int*)d_in[1];
    const int* dst = (const int*)d_in[2];
    const float* W = (const float*)d_in[3];
    const float* att_s = (const float*)d_in[4];
    const float* att_d = (const float*)d_in[5];
    const float* bias = (const float*)d_in[6];
    const float* Wr = (const float*)d_in[7];
    const float* br = (const float*)d_in[8];

    float* out = (float*)d_out;
    float* Xall = out + (size_t)N_NODES * NCLASS;
    float* Yall = Xall + (size_t)N_NODES * LSTRIDE;

    char* p = (char*)d_ws;
    auto alloc = [&](size_t bytes) -> char* {
        char* r = p;
        p += (bytes + 255) & ~(size_t)255;
        return r;
    };
    u16* XbfA = (u16*)alloc((size_t)N_NODES * 128 * 2);
    u16* XbfB = (u16*)alloc((size_t)N_NODES * 128 * 2);
    u16* Wt = (u16*)alloc(512 * 128 * 2);
    float* a_sA = (float*)alloc((size_t)N_NODES * 4 * 4);
    float* a_dA = (float*)alloc((size_t)N_NODES * 4 * 4);
    float* a_sB = (float*)alloc((size_t)N_NODES * 4 * 4);
    float* a_dB = (float*)alloc((size_t)N_NODES * 4 * 4);
    float* Vs = (float*)alloc(128 * 4 * 4);
    float* Vd = (float*)alloc(128 * 4 * 4);
    int* indptr = (int*)alloc((N_NODES + 1) * 4);
    int* cursor = (int*)alloc(N_NODES * 4);
    int* counts = (int*)alloc(N_NODES * 4);
    int* esrc = (int*)alloc((size_t)(NE + N_NODES) * 4);

    hipMemsetAsync(counts, 0, N_NODES * sizeof(int), stream);
    k_pre1<<<P1_INIT + P1_TRANS + P1_FOLD + P1_COUNT, 256, 0, stream>>>(
        x, dst, W, att_s, att_d, XbfA, Xall, Yall, Wt, Vs, Vd, counts);
    k_pre2<<<1251, 1024, 0, stream>>>(counts, indptr, cursor, x, Vs, Vd, a_sA, a_dA);
    k_scatter<<<(NE + N_NODES + 255) / 256, 256, 0, stream>>>(src, dst, cursor, esrc);

    for (int layer = 0; layer < NLAYERS; layer++) {
        const float* as_r = (layer & 1) ? a_sB : a_sA;
        const float* ad_r = (layer & 1) ? a_dB : a_dA;
        float* as_w = (layer & 1) ? a_sA : a_sB;
        float* ad_w = (layer & 1) ? a_dA : a_dB;
        const u16* xr = (layer & 1) ? XbfB : XbfA;
        u16* xw = (layer & 1) ? XbfA : XbfB;
        k_layer<<<N_NODES / 16, 512, 0, stream>>>(indptr, esrc, as_r, ad_r, xr, Wt, bias,
                                                  Xall, Yall, xw, as_w, ad_w, Vs, Vd, layer,
                                                  (layer + 1 < NLAYERS) ? 1 : 0);
    }
    k_out<<<N_NODES / 4, 256, 0, stream>>>(Xall, Wr, br, out);
}